// Round 1
// baseline (971.908 us; speedup 1.0000x reference)
//
#include <hip/hip_runtime.h>
#include <hip/hip_bf16.h>

// SmallGAT: 2x GATConv(128->128, heads=2, concat) + relu, mean-pool per graph, FC 128->32.
// Strategy: CSR (counting-sort by dst) built once per call; softmax stats via atomics;
// aggregation = block-per-node register accumulation (no fp32 scatter atomics).

#define NEG_SLOPE 0.2f

__device__ __forceinline__ float lrelu(float x) { return x > 0.f ? x : NEG_SLOPE * x; }

// order-preserving float<->uint map for atomicMax on floats (incl. negatives)
__device__ __forceinline__ unsigned f2o(float f) {
    unsigned u = __float_as_uint(f);
    return (u & 0x80000000u) ? ~u : (u | 0x80000000u);
}
__device__ __forceinline__ float o2f(unsigned u) {
    return __uint_as_float((u & 0x80000000u) ? (u & 0x7fffffffu) : ~u);
}

// ---------------- CSR build ----------------
__global__ void csr_deg_init(int* deg, int N) {
    int n = blockIdx.x * 256 + threadIdx.x;
    if (n < N) deg[n] = 1;  // self loop
}

__global__ void csr_hist(const int* __restrict__ ei, int* __restrict__ deg, int E) {
    int e = blockIdx.x * 256 + threadIdx.x;
    if (e < E) atomicAdd(&deg[ei[E + e]], 1);
}

__global__ __launch_bounds__(1024) void scan_kernel(const int* __restrict__ deg, int* __restrict__ offs, int N) {
    __shared__ int sums[1024];
    __shared__ int carry_s;
    int t = threadIdx.x;
    if (t == 0) carry_s = 0;
    __syncthreads();
    const int CH = 8192;  // 1024 threads x 8
    for (int base = 0; base < N; base += CH) {
        int v[8];
        int tot = 0;
#pragma unroll
        for (int i = 0; i < 8; ++i) {
            int n = base + t * 8 + i;
            v[i] = (n < N) ? deg[n] : 0;
            tot += v[i];
        }
        sums[t] = tot;
        __syncthreads();
        for (int off = 1; off < 1024; off <<= 1) {
            int x = (t >= off) ? sums[t - off] : 0;
            __syncthreads();
            sums[t] += x;
            __syncthreads();
        }
        int excl = sums[t] - tot;
        int carry = carry_s;
        int run = carry + excl;
#pragma unroll
        for (int i = 0; i < 8; ++i) {
            int n = base + t * 8 + i;
            if (n < N) offs[n] = run;
            run += v[i];
        }
        __syncthreads();
        if (t == 1023) carry_s = carry + sums[1023];
        __syncthreads();
    }
    if (t == 0) offs[N] = carry_s;
}

__global__ void csr_self_place(const int* __restrict__ offs, int* __restrict__ ssrc,
                               int* __restrict__ seid, int* __restrict__ cursor, int N, int E) {
    int n = blockIdx.x * 256 + threadIdx.x;
    if (n >= N) return;
    int o = offs[n];
    ssrc[o] = n;
    seid[o] = E + n;  // self-loop edge id
    cursor[n] = o + 1;
}

__global__ void csr_scatter(const int* __restrict__ ei, int* __restrict__ cursor,
                            int* __restrict__ ssrc, int* __restrict__ seid, int E) {
    int e = blockIdx.x * 256 + threadIdx.x;
    if (e >= E) return;
    int d = ei[E + e];
    int pos = atomicAdd(&cursor[d], 1);
    ssrc[pos] = ei[e];
    seid[pos] = e;
}

// ---------------- dense: W transpose + GEMM ----------------
__global__ void transpose_w(const float* __restrict__ W, float* __restrict__ Wt) {
    int i = blockIdx.x * 256 + threadIdx.x;  // i = k*128 + n
    if (i >= 16384) return;
    int n = i & 127, k = i >> 7;
    Wt[i] = W[n * 128 + k];
}

#define GBM 32
// out[m][n] = sum_k A[m][k] * W[n][k];   Wt[k][n] pre-transposed
__global__ __launch_bounds__(256) void gemm_kernel(const float* __restrict__ A, const float* __restrict__ Wt,
                                                   float* __restrict__ out, int M) {
    __shared__ float As[GBM * 128];
    __shared__ float Ws[128 * 128];
    int tid = threadIdx.x;
    int m0 = blockIdx.x * GBM;
    const float4* Wt4 = (const float4*)Wt;
    float4* Ws4 = (float4*)Ws;
#pragma unroll
    for (int i = 0; i < 16; ++i) Ws4[tid + i * 256] = Wt4[tid + i * 256];
#pragma unroll
    for (int i = 0; i < 4; ++i) {
        int j = tid + i * 256;    // float4 index 0..1023
        int r = j >> 5;           // row 0..31
        int c4 = (j & 31) << 2;   // col
        int m = m0 + r;
        float4 v = make_float4(0.f, 0.f, 0.f, 0.f);
        if (m < M) v = *(const float4*)(A + m * 128 + c4);
        *(float4*)(As + r * 128 + c4) = v;
    }
    __syncthreads();
    int rg = tid >> 4;  // 0..15 -> rows rg*2, rg*2+1
    int ct = tid & 15;  // cols ct + 16*j
    float acc0[8] = {0, 0, 0, 0, 0, 0, 0, 0};
    float acc1[8] = {0, 0, 0, 0, 0, 0, 0, 0};
#pragma unroll 4
    for (int k = 0; k < 128; ++k) {
        float a0 = As[(rg * 2 + 0) * 128 + k];
        float a1 = As[(rg * 2 + 1) * 128 + k];
#pragma unroll
        for (int j = 0; j < 8; ++j) {
            float b = Ws[k * 128 + ct + j * 16];
            acc0[j] += a0 * b;
            acc1[j] += a1 * b;
        }
    }
    int ma = m0 + rg * 2, mb = ma + 1;
    if (ma < M) {
#pragma unroll
        for (int j = 0; j < 8; ++j) out[ma * 128 + ct + j * 16] = acc0[j];
    }
    if (mb < M) {
#pragma unroll
        for (int j = 0; j < 8; ++j) out[mb * 128 + ct + j * 16] = acc1[j];
    }
}

// ---------------- attention ----------------
// a_src[n][h] = dot(XL[n, h*64: h*64+64], att_s[h]);  same for a_dst
__global__ __launch_bounds__(128) void att_kernel(const float* __restrict__ XL, const float* __restrict__ att_s,
                                                  const float* __restrict__ att_d, float* __restrict__ a_src,
                                                  float* __restrict__ a_dst, int N) {
    int n = blockIdx.x;
    int t = threadIdx.x;  // 0..127 ; wave 0 = head 0, wave 1 = head 1
    int h = t >> 6, c = t & 63;
    float v = XL[n * 128 + t];
    float ps = v * att_s[t];
    float pd = v * att_d[t];
#pragma unroll
    for (int off = 32; off > 0; off >>= 1) {
        ps += __shfl_down(ps, off);
        pd += __shfl_down(pd, off);
    }
    if (c == 0) {
        a_src[n * 2 + h] = ps;
        a_dst[n * 2 + h] = pd;
    }
}

__global__ void attn_init(unsigned* __restrict__ amax_u, float* __restrict__ denom, int N2) {
    int i = blockIdx.x * 256 + threadIdx.x;
    if (i < N2) {
        amax_u[i] = 0x007FFFFFu;  // f2o(-inf)
        denom[i] = 0.f;
    }
}

__global__ void edge_alpha(const int* __restrict__ ei, const float* __restrict__ a_src,
                           const float* __restrict__ a_dst, float* __restrict__ exst,
                           unsigned* __restrict__ amax_u, int N, int E) {
    int e = blockIdx.x * 256 + threadIdx.x;
    if (e >= E + N) return;
    int s, d;
    if (e < E) {
        s = ei[e];
        d = ei[E + e];
    } else {
        s = e - E;
        d = s;
    }
    float2 av = ((const float2*)a_src)[s];
    float2 bv = ((const float2*)a_dst)[d];
    float al0 = lrelu(av.x + bv.x);
    float al1 = lrelu(av.y + bv.y);
    ((float2*)exst)[e] = make_float2(al0, al1);
    atomicMax(&amax_u[d * 2 + 0], f2o(al0));
    atomicMax(&amax_u[d * 2 + 1], f2o(al1));
}

__global__ void edge_denom(const int* __restrict__ ei, float* __restrict__ exst,
                           const unsigned* __restrict__ amax_u, float* __restrict__ denom, int N, int E) {
    int e = blockIdx.x * 256 + threadIdx.x;
    if (e >= E + N) return;
    int d = (e < E) ? ei[E + e] : (e - E);
    float2 al = ((const float2*)exst)[e];
    float e0 = expf(al.x - o2f(amax_u[d * 2 + 0]));
    float e1 = expf(al.y - o2f(amax_u[d * 2 + 1]));
    ((float2*)exst)[e] = make_float2(e0, e1);
    atomicAdd(&denom[d * 2 + 0], e0);
    atomicAdd(&denom[d * 2 + 1], e1);
}

// block-per-node aggregation: out[n][t] = relu(bias[t] + sum_j coeff_j * XL[src_j][t])
__global__ __launch_bounds__(128) void aggregate_kernel(const float* __restrict__ XL, const float* __restrict__ exst,
                                                        const float* __restrict__ denom, const int* __restrict__ offs,
                                                        const int* __restrict__ ssrc, const int* __restrict__ seid,
                                                        const float* __restrict__ bias, float* __restrict__ out, int N) {
    int n = blockIdx.x;
    int t = threadIdx.x;  // channel 0..127
    int h = t >> 6;
    float inv = 1.f / fmaxf(denom[n * 2 + h], 1e-16f);
    float acc = 0.f;
    int j0 = offs[n], j1 = offs[n + 1];
    for (int j = j0; j < j1; ++j) {
        int s = ssrc[j];
        int eid = seid[j];
        float c = exst[eid * 2 + h] * inv;
        acc += c * XL[s * 128 + t];
    }
    out[n * 128 + t] = fmaxf(acc + bias[t], 0.f);
}

// ---------------- pooling + FC ----------------
#define PNODES 256
__global__ __launch_bounds__(128) void pool_kernel(const float* __restrict__ H, const int* __restrict__ batch,
                                                   float* __restrict__ pooled, int* __restrict__ counts, int N) {
    int t = threadIdx.x;
    int base = blockIdx.x * PNODES;
    float acc = 0.f;
    int cur = -1;
    int runstart = 0;
    int lim = min(PNODES, N - base);
    for (int i = 0; i < lim; ++i) {
        int n = base + i;
        int g = batch[n];
        if (g != cur) {
            if (cur >= 0) {
                atomicAdd(&pooled[cur * 128 + t], acc);
                if (t == 0) atomicAdd(&counts[cur], i - runstart);
            }
            cur = g;
            acc = 0.f;
            runstart = i;
        }
        acc += H[n * 128 + t];
    }
    if (cur >= 0) {
        atomicAdd(&pooled[cur * 128 + t], acc);
        if (t == 0) atomicAdd(&counts[cur], lim - runstart);
    }
}

__global__ void final_kernel(const float* __restrict__ pooled, const int* __restrict__ counts,
                             const float* __restrict__ fc_w, const float* __restrict__ fc_b,
                             float* __restrict__ out) {
    int idx = blockIdx.x * 256 + threadIdx.x;
    if (idx >= 64 * 32) return;
    int g = idx >> 5, k = idx & 31;
    float invc = 1.f / fmaxf((float)counts[g], 1.f);
    float s = 0.f;
#pragma unroll 4
    for (int c = 0; c < 128; ++c) s += pooled[g * 128 + c] * fc_w[k * 128 + c];
    out[idx] = s * invc + fc_b[k];
}

// ---------------- host ----------------
extern "C" void kernel_launch(void* const* d_in, const int* in_sizes, int n_in,
                              void* d_out, int out_size, void* d_ws, size_t ws_size,
                              hipStream_t stream) {
    const float* x = (const float*)d_in[0];
    const int* ei = (const int*)d_in[1];
    const int* batch = (const int*)d_in[2];
    const float* W1 = (const float*)d_in[3];
    const float* as1 = (const float*)d_in[4];
    const float* ad1 = (const float*)d_in[5];
    const float* b1 = (const float*)d_in[6];
    const float* W2 = (const float*)d_in[7];
    const float* as2 = (const float*)d_in[8];
    const float* ad2 = (const float*)d_in[9];
    const float* b2 = (const float*)d_in[10];
    const float* fcw = (const float*)d_in[11];
    const float* fcb = (const float*)d_in[12];
    float* out = (float*)d_out;

    const int N = in_sizes[0] / 128;  // 50000
    const int E = in_sizes[1] / 2;    // 800000
    const int EN = E + N;

    char* p = (char*)d_ws;
    auto alloc = [&](size_t bytes) -> char* {
        char* r = p;
        p += (bytes + 255) & ~(size_t)255;
        return r;
    };
    float* XL = (float*)alloc((size_t)N * 128 * 4);
    float* H = (float*)alloc((size_t)N * 128 * 4);
    float* a_src = (float*)alloc((size_t)N * 2 * 4);
    float* a_dst = (float*)alloc((size_t)N * 2 * 4);
    float* exst = (float*)alloc((size_t)EN * 2 * 4);
    unsigned* amax_u = (unsigned*)alloc((size_t)N * 2 * 4);
    float* denom = (float*)alloc((size_t)N * 2 * 4);
    int* deg = (int*)alloc((size_t)N * 4);
    int* offs = (int*)alloc((size_t)(N + 1) * 4);
    int* cursor = (int*)alloc((size_t)N * 4);
    int* ssrc = (int*)alloc((size_t)EN * 4);
    int* seid = (int*)alloc((size_t)EN * 4);
    float* Wt = (float*)alloc(16384 * 4);
    float* pooled = (float*)alloc(8192 * 4);
    int* counts = (int*)alloc(64 * 4);

    const int TB = 256;
    int gN = (N + TB - 1) / TB;
    int gE = (E + TB - 1) / TB;
    int gEN = (EN + TB - 1) / TB;
    int gN2 = (2 * N + TB - 1) / TB;
    int gGemm = (N + GBM - 1) / GBM;

    // CSR build (shared by both layers)
    csr_deg_init<<<gN, TB, 0, stream>>>(deg, N);
    csr_hist<<<gE, TB, 0, stream>>>(ei, deg, E);
    scan_kernel<<<1, 1024, 0, stream>>>(deg, offs, N);
    csr_self_place<<<gN, TB, 0, stream>>>(offs, ssrc, seid, cursor, N, E);
    csr_scatter<<<gE, TB, 0, stream>>>(ei, cursor, ssrc, seid, E);

    // ---- layer 1 ----
    transpose_w<<<64, TB, 0, stream>>>(W1, Wt);
    gemm_kernel<<<gGemm, TB, 0, stream>>>(x, Wt, XL, N);
    att_kernel<<<N, 128, 0, stream>>>(XL, as1, ad1, a_src, a_dst, N);
    attn_init<<<gN2, TB, 0, stream>>>(amax_u, denom, 2 * N);
    edge_alpha<<<gEN, TB, 0, stream>>>(ei, a_src, a_dst, exst, amax_u, N, E);
    edge_denom<<<gEN, TB, 0, stream>>>(ei, exst, amax_u, denom, N, E);
    aggregate_kernel<<<N, 128, 0, stream>>>(XL, exst, denom, offs, ssrc, seid, b1, H, N);

    // ---- layer 2 ----
    transpose_w<<<64, TB, 0, stream>>>(W2, Wt);
    gemm_kernel<<<gGemm, TB, 0, stream>>>(H, Wt, XL, N);
    att_kernel<<<N, 128, 0, stream>>>(XL, as2, ad2, a_src, a_dst, N);
    attn_init<<<gN2, TB, 0, stream>>>(amax_u, denom, 2 * N);
    edge_alpha<<<gEN, TB, 0, stream>>>(ei, a_src, a_dst, exst, amax_u, N, E);
    edge_denom<<<gEN, TB, 0, stream>>>(ei, exst, amax_u, denom, N, E);
    aggregate_kernel<<<N, 128, 0, stream>>>(XL, exst, denom, offs, ssrc, seid, b2, H, N);

    // ---- pool + FC ----
    hipMemsetAsync(pooled, 0, 8192 * 4 + 256, stream);  // pooled + counts (contiguous)
    pool_kernel<<<(N + PNODES - 1) / PNODES, 128, 0, stream>>>(H, batch, pooled, counts, N);
    final_kernel<<<8, TB, 0, stream>>>(pooled, counts, fcw, fcb, out);
}

// Round 2
// 567.592 us; speedup vs baseline: 1.7123x; 1.7123x over previous
//
#include <hip/hip_runtime.h>
#include <hip/hip_bf16.h>

// SmallGAT: 2x GATConv(128->128, heads=2, concat) + relu, mean-pool per graph, FC 128->32.
// R2: fused per-node softmax+aggregate (no edge atomics, no exst); register-tiled GEMM.

#define NEG_SLOPE 0.2f

__device__ __forceinline__ float lrelu(float x) { return x > 0.f ? x : NEG_SLOPE * x; }

// ---------------- CSR build ----------------
__global__ void csr_deg_init(int* deg, int N) {
    int n = blockIdx.x * 256 + threadIdx.x;
    if (n < N) deg[n] = 1;  // self loop
}

__global__ void csr_hist(const int* __restrict__ ei, int* __restrict__ deg, int E) {
    int e = blockIdx.x * 256 + threadIdx.x;
    if (e < E) atomicAdd(&deg[ei[E + e]], 1);
}

__global__ __launch_bounds__(1024) void scan_kernel(const int* __restrict__ deg, int* __restrict__ offs, int N) {
    __shared__ int sums[1024];
    __shared__ int carry_s;
    int t = threadIdx.x;
    if (t == 0) carry_s = 0;
    __syncthreads();
    const int CH = 8192;  // 1024 threads x 8
    for (int base = 0; base < N; base += CH) {
        int v[8];
        int tot = 0;
#pragma unroll
        for (int i = 0; i < 8; ++i) {
            int n = base + t * 8 + i;
            v[i] = (n < N) ? deg[n] : 0;
            tot += v[i];
        }
        sums[t] = tot;
        __syncthreads();
        for (int off = 1; off < 1024; off <<= 1) {
            int x = (t >= off) ? sums[t - off] : 0;
            __syncthreads();
            sums[t] += x;
            __syncthreads();
        }
        int excl = sums[t] - tot;
        int carry = carry_s;
        int run = carry + excl;
#pragma unroll
        for (int i = 0; i < 8; ++i) {
            int n = base + t * 8 + i;
            if (n < N) offs[n] = run;
            run += v[i];
        }
        __syncthreads();
        if (t == 1023) carry_s = carry + sums[1023];
        __syncthreads();
    }
    if (t == 0) offs[N] = carry_s;
}

__global__ void csr_self_place(const int* __restrict__ offs, int* __restrict__ ssrc,
                               int* __restrict__ cursor, int N) {
    int n = blockIdx.x * 256 + threadIdx.x;
    if (n >= N) return;
    int o = offs[n];
    ssrc[o] = n;  // self-loop
    cursor[n] = o + 1;
}

__global__ void csr_scatter(const int* __restrict__ ei, int* __restrict__ cursor,
                            int* __restrict__ ssrc, int E) {
    int e = blockIdx.x * 256 + threadIdx.x;
    if (e >= E) return;
    int d = ei[E + e];
    int pos = atomicAdd(&cursor[d], 1);
    ssrc[pos] = ei[e];
}

// ---------------- dense: W transpose + GEMM ----------------
__global__ void transpose_w(const float* __restrict__ W, float* __restrict__ Wt) {
    int i = blockIdx.x * 256 + threadIdx.x;  // i = k*128 + n
    if (i >= 16384) return;
    int n = i & 127, k = i >> 7;
    Wt[i] = W[n * 128 + k];
}

#define GBM 32
// out[m][n] = sum_k A[m][k] * Wt[k][n]
__global__ __launch_bounds__(256) void gemm_kernel(const float* __restrict__ A, const float* __restrict__ Wt,
                                                   float* __restrict__ out, int M) {
    __shared__ float Ws[128 * 128];   // [k][n], 64KB
    __shared__ float As[GBM][128];    // row-major, 16KB
    int tid = threadIdx.x;
    int m0 = blockIdx.x * GBM;
    const float4* Wt4 = (const float4*)Wt;
    float4* Ws4 = (float4*)Ws;
#pragma unroll
    for (int i = 0; i < 16; ++i) Ws4[tid + i * 256] = Wt4[tid + i * 256];
#pragma unroll
    for (int i = 0; i < 4; ++i) {
        int j = tid + i * 256;    // 0..1023 float4 slots: 32 rows x 32
        int r = j >> 5;
        int c4 = (j & 31) << 2;
        int m = m0 + r;
        float4 v = make_float4(0.f, 0.f, 0.f, 0.f);
        if (m < M) v = *(const float4*)(A + (size_t)m * 128 + c4);
        *(float4*)(&As[r][c4]) = v;
    }
    __syncthreads();
    int rg = tid >> 5;  // 0..7 -> rows rg*4..rg*4+3
    int ct = tid & 31;  // cols ct*4..ct*4+3
    float acc[4][4] = {{0.f}};
#pragma unroll 4
    for (int k = 0; k < 128; ++k) {
        float4 b = *(const float4*)(&Ws[k * 128 + ct * 4]);
        float a0 = As[rg * 4 + 0][k];
        float a1 = As[rg * 4 + 1][k];
        float a2 = As[rg * 4 + 2][k];
        float a3 = As[rg * 4 + 3][k];
        acc[0][0] += a0 * b.x; acc[0][1] += a0 * b.y; acc[0][2] += a0 * b.z; acc[0][3] += a0 * b.w;
        acc[1][0] += a1 * b.x; acc[1][1] += a1 * b.y; acc[1][2] += a1 * b.z; acc[1][3] += a1 * b.w;
        acc[2][0] += a2 * b.x; acc[2][1] += a2 * b.y; acc[2][2] += a2 * b.z; acc[2][3] += a2 * b.w;
        acc[3][0] += a3 * b.x; acc[3][1] += a3 * b.y; acc[3][2] += a3 * b.z; acc[3][3] += a3 * b.w;
    }
#pragma unroll
    for (int i = 0; i < 4; ++i) {
        int m = m0 + rg * 4 + i;
        if (m < M) {
            float4 v = make_float4(acc[i][0], acc[i][1], acc[i][2], acc[i][3]);
            *(float4*)(out + (size_t)m * 128 + ct * 4) = v;
        }
    }
}

// ---------------- attention dots ----------------
__global__ __launch_bounds__(128) void att_kernel(const float* __restrict__ XL, const float* __restrict__ att_s,
                                                  const float* __restrict__ att_d, float* __restrict__ a_src,
                                                  float* __restrict__ a_dst, int N) {
    int n = blockIdx.x;
    int t = threadIdx.x;  // wave 0 = head 0, wave 1 = head 1
    int h = t >> 6, c = t & 63;
    float v = XL[(size_t)n * 128 + t];
    float ps = v * att_s[t];
    float pd = v * att_d[t];
#pragma unroll
    for (int off = 32; off > 0; off >>= 1) {
        ps += __shfl_down(ps, off);
        pd += __shfl_down(pd, off);
    }
    if (c == 0) {
        a_src[n * 2 + h] = ps;
        a_dst[n * 2 + h] = pd;
    }
}

// ---------------- fused per-node softmax + aggregate ----------------
// wave h owns head h: computes softmax coeffs into LDS, then accumulates channels h*64..h*64+63.
// No barriers, no atomics.
#define MAXD 512
__global__ __launch_bounds__(128) void gat_node_kernel(const float* __restrict__ XL, const float* __restrict__ a_src,
                                                       const float* __restrict__ a_dst, const int* __restrict__ offs,
                                                       const int* __restrict__ ssrc, const float* __restrict__ bias,
                                                       float* __restrict__ out, int N) {
    __shared__ float coeff[2][MAXD];
    int n = blockIdx.x;
    int t = threadIdx.x;
    int h = t >> 6, lane = t & 63;
    int j0 = offs[n], j1 = offs[n + 1];
    int deg = j1 - j0;
    float ad = a_dst[n * 2 + h];
    float acc = 0.f;
    if (deg <= MAXD) {
        // phase A: alphas -> LDS, running max
        float m = -1e30f;
        for (int k = lane; k < deg; k += 64) {
            int s = ssrc[j0 + k];
            float al = lrelu(a_src[s * 2 + h] + ad);
            coeff[h][k] = al;
            m = fmaxf(m, al);
        }
#pragma unroll
        for (int off = 32; off > 0; off >>= 1) m = fmaxf(m, __shfl_xor(m, off));
        float sum = 0.f;
        for (int k = lane; k < deg; k += 64) {
            float e = __expf(coeff[h][k] - m);
            coeff[h][k] = e;
            sum += e;
        }
#pragma unroll
        for (int off = 32; off > 0; off >>= 1) sum += __shfl_xor(sum, off);
        float inv = 1.f / fmaxf(sum, 1e-16f);
        // phase B: gather + weighted accumulate (2-wide for load overlap)
        int j = 0;
        for (; j + 1 < deg; j += 2) {
            int s0 = ssrc[j0 + j];
            int s1 = ssrc[j0 + j + 1];
            float c0 = coeff[h][j] * inv;
            float c1 = coeff[h][j + 1] * inv;
            acc += c0 * XL[(size_t)s0 * 128 + t] + c1 * XL[(size_t)s1 * 128 + t];
        }
        if (j < deg) {
            int s = ssrc[j0 + j];
            acc += coeff[h][j] * inv * XL[(size_t)s * 128 + t];
        }
    } else {
        // streaming fallback (deg > MAXD; effectively never for this graph, kept for correctness)
        float m = -1e30f;
        for (int k = lane; k < deg; k += 64) {
            int s = ssrc[j0 + k];
            m = fmaxf(m, lrelu(a_src[s * 2 + h] + ad));
        }
#pragma unroll
        for (int off = 32; off > 0; off >>= 1) m = fmaxf(m, __shfl_xor(m, off));
        float sum = 0.f;
        for (int k = lane; k < deg; k += 64) {
            int s = ssrc[j0 + k];
            sum += __expf(lrelu(a_src[s * 2 + h] + ad) - m);
        }
#pragma unroll
        for (int off = 32; off > 0; off >>= 1) sum += __shfl_xor(sum, off);
        float inv = 1.f / fmaxf(sum, 1e-16f);
        for (int j = 0; j < deg; ++j) {
            int s = ssrc[j0 + j];
            float c = __expf(lrelu(a_src[s * 2 + h] + ad) - m) * inv;
            acc += c * XL[(size_t)s * 128 + t];
        }
    }
    out[(size_t)n * 128 + t] = fmaxf(acc + bias[t], 0.f);
}

// ---------------- pooling + FC ----------------
#define PNODES 256
__global__ __launch_bounds__(128) void pool_kernel(const float* __restrict__ H, const int* __restrict__ batch,
                                                   float* __restrict__ pooled, int* __restrict__ counts, int N) {
    int t = threadIdx.x;
    int base = blockIdx.x * PNODES;
    float acc = 0.f;
    int cur = -1;
    int runstart = 0;
    int lim = min(PNODES, N - base);
    for (int i = 0; i < lim; ++i) {
        int n = base + i;
        int g = batch[n];
        if (g != cur) {
            if (cur >= 0) {
                atomicAdd(&pooled[cur * 128 + t], acc);
                if (t == 0) atomicAdd(&counts[cur], i - runstart);
            }
            cur = g;
            acc = 0.f;
            runstart = i;
        }
        acc += H[(size_t)n * 128 + t];
    }
    if (cur >= 0) {
        atomicAdd(&pooled[cur * 128 + t], acc);
        if (t == 0) atomicAdd(&counts[cur], lim - runstart);
    }
}

__global__ void final_kernel(const float* __restrict__ pooled, const int* __restrict__ counts,
                             const float* __restrict__ fc_w, const float* __restrict__ fc_b,
                             float* __restrict__ out) {
    int idx = blockIdx.x * 256 + threadIdx.x;
    if (idx >= 64 * 32) return;
    int g = idx >> 5, k = idx & 31;
    float invc = 1.f / fmaxf((float)counts[g], 1.f);
    float s = 0.f;
#pragma unroll 4
    for (int c = 0; c < 128; ++c) s += pooled[g * 128 + c] * fc_w[k * 128 + c];
    out[idx] = s * invc + fc_b[k];
}

// ---------------- host ----------------
extern "C" void kernel_launch(void* const* d_in, const int* in_sizes, int n_in,
                              void* d_out, int out_size, void* d_ws, size_t ws_size,
                              hipStream_t stream) {
    const float* x = (const float*)d_in[0];
    const int* ei = (const int*)d_in[1];
    const int* batch = (const int*)d_in[2];
    const float* W1 = (const float*)d_in[3];
    const float* as1 = (const float*)d_in[4];
    const float* ad1 = (const float*)d_in[5];
    const float* b1 = (const float*)d_in[6];
    const float* W2 = (const float*)d_in[7];
    const float* as2 = (const float*)d_in[8];
    const float* ad2 = (const float*)d_in[9];
    const float* b2 = (const float*)d_in[10];
    const float* fcw = (const float*)d_in[11];
    const float* fcb = (const float*)d_in[12];
    float* out = (float*)d_out;

    const int N = in_sizes[0] / 128;  // 50000
    const int E = in_sizes[1] / 2;    // 800000
    const int EN = E + N;

    char* p = (char*)d_ws;
    auto alloc = [&](size_t bytes) -> char* {
        char* r = p;
        p += (bytes + 255) & ~(size_t)255;
        return r;
    };
    float* XL = (float*)alloc((size_t)N * 128 * 4);
    float* H = (float*)alloc((size_t)N * 128 * 4);
    float* a_src = (float*)alloc((size_t)N * 2 * 4);
    float* a_dst = (float*)alloc((size_t)N * 2 * 4);
    int* deg = (int*)alloc((size_t)N * 4);
    int* offs = (int*)alloc((size_t)(N + 1) * 4);
    int* cursor = (int*)alloc((size_t)N * 4);
    int* ssrc = (int*)alloc((size_t)EN * 4);
    float* Wt = (float*)alloc(16384 * 4);
    float* pooled = (float*)alloc(8192 * 4);
    int* counts = (int*)alloc(64 * 4);

    const int TB = 256;
    int gN = (N + TB - 1) / TB;
    int gE = (E + TB - 1) / TB;
    int gGemm = (N + GBM - 1) / GBM;

    // CSR build (shared by both layers)
    csr_deg_init<<<gN, TB, 0, stream>>>(deg, N);
    csr_hist<<<gE, TB, 0, stream>>>(ei, deg, E);
    scan_kernel<<<1, 1024, 0, stream>>>(deg, offs, N);
    csr_self_place<<<gN, TB, 0, stream>>>(offs, ssrc, cursor, N);
    csr_scatter<<<gE, TB, 0, stream>>>(ei, cursor, ssrc, E);

    // ---- layer 1 ----
    transpose_w<<<64, TB, 0, stream>>>(W1, Wt);
    gemm_kernel<<<gGemm, TB, 0, stream>>>(x, Wt, XL, N);
    att_kernel<<<N, 128, 0, stream>>>(XL, as1, ad1, a_src, a_dst, N);
    gat_node_kernel<<<N, 128, 0, stream>>>(XL, a_src, a_dst, offs, ssrc, b1, H, N);

    // ---- layer 2 ----
    transpose_w<<<64, TB, 0, stream>>>(W2, Wt);
    gemm_kernel<<<gGemm, TB, 0, stream>>>(H, Wt, XL, N);
    att_kernel<<<N, 128, 0, stream>>>(XL, as2, ad2, a_src, a_dst, N);
    gat_node_kernel<<<N, 128, 0, stream>>>(XL, a_src, a_dst, offs, ssrc, b2, H, N);

    // ---- pool + FC ----
    hipMemsetAsync(pooled, 0, 8192 * 4 + 256, stream);  // pooled + counts (contiguous)
    pool_kernel<<<(N + PNODES - 1) / PNODES, 128, 0, stream>>>(H, batch, pooled, counts, N);
    final_kernel<<<8, TB, 0, stream>>>(pooled, counts, fcw, fcb, out);
}